// Round 6
// baseline (216.829 us; speedup 1.0000x reference)
//
#include <hip/hip_runtime.h>
#include <hip/hip_bf16.h>
#include <hip/hip_cooperative_groups.h>

namespace cg = cooperative_groups;

typedef __attribute__((ext_vector_type(8))) __bf16 bf16x8;
typedef __attribute__((ext_vector_type(4))) float f32x4;
typedef __attribute__((ext_vector_type(2))) float f32x2;

#define DEVI static __device__ __forceinline__

DEVI unsigned short f2bf(float f) {
    union { float f; unsigned int u; } v; v.f = f;
    unsigned int u = v.u;
    u += 0x7FFFu + ((u >> 16) & 1u);   // RNE
    return (unsigned short)(u >> 16);
}

// ===========================================================================
// Shared index maps (verified passing in rounds 3/4):
//  WcatT[256][192]: col c<128 -> W_l row c, c>=128 -> W_r row c-128.
//  Packed K order = window order [x(n-1) | x(n) | x(n+1)].
//   W_l map: 0:64<-feat 64:128, 64:128<-feat 0:64, 128:192<-feat 128:192
//   W_r map: 0:64<-feat 128:192, 64:192<-feat 0:128
//  WtT[256][128]: c = k*128+g, WtT[c][h] = W_bil[k][h][g]
//  MFMA 16x16x32 bf16: A[m=lane&15][k=q*8+j], B[k=q*8+j][n=lane&15],
//                      D[row=q*4+r][col=lane&15]
// ===========================================================================

// ---------------------------------------------------------------------------
// Fused cooperative kernel: 256 blocks x 256 threads = 1 block/CU (maximally
// conservative co-residency). Round-5 coop launch @512 blocks failed silently;
// this round checks the return code and uses 1 block/CU.
// ---------------------------------------------------------------------------
__global__ __launch_bounds__(256) void fused_kernel(
    const float* __restrict__ x,
    const float* __restrict__ Wl,
    const float* __restrict__ bl,
    const float* __restrict__ Wr,
    const float* __restrict__ br,
    const float* __restrict__ Wb,
    const float* __restrict__ bbil,
    float* __restrict__ out,
    unsigned short* __restrict__ WcatT,
    unsigned short* __restrict__ WtT,
    unsigned short* __restrict__ t_ws,    // [B*N][256], c = k*128+g
    unsigned short* __restrict__ hr_ws)   // [B*N][128]
{
    cg::grid_group grid = cg::this_grid();

    __shared__ unsigned short xwin[34*72];   // rows padded 64->72
    __shared__ unsigned short Hbuf[32*264];  // 256 -> 264 pad
    __shared__ unsigned short Tbuf[32*264];

    const int tid = threadIdx.x;
    const int blk = blockIdx.x;              // 256 blocks

    // ======================= Phase 0: weight prep ==========================
    const int TOT = 256*192 + 256*128;       // 81920 > 65536 threads -> loop
    for (int i = blk*256 + tid; i < TOT; i += 256*256) {
        if (i < 256*192) {
            int c = i / 192, kk = i % 192;
            float v;
            if (c < 128) {
                int orig = (kk < 64) ? (kk + 64) : ((kk < 128) ? (kk - 64) : kk);
                v = Wl[c*192 + orig];
            } else {
                int orig = (kk < 64) ? (kk + 128) : (kk - 64);
                v = Wr[(c-128)*192 + orig];
            }
            WcatT[i] = f2bf(v);
        } else {
            int j = i - 256*192;
            int c = j >> 7, h = j & 127;
            int k = c >> 7, g = c & 127;
            WtT[j] = f2bf(Wb[(k*128 + h)*128 + g]);
        }
    }
    __threadfence();
    grid.sync();

    // ======================= Phase 1: MLPs + t (32 rows/block) =============
    {
        const int b1 = blk >> 5;             // 32 blocks per batch
        const int n0 = (blk & 31) << 5;

        for (int c = tid; c < 34*16; c += 256) {
            int row = c >> 4, ch = c & 15;
            int n = n0 - 1 + row;
            float4 v = make_float4(0.f, 0.f, 0.f, 0.f);
            if (n >= 0 && n < 1024)
                v = ((const float4*)(x + ((size_t)b1*1024 + n)*64))[ch];
            unsigned short* d = &xwin[row*72 + ch*4];
            d[0]=f2bf(v.x); d[1]=f2bf(v.y); d[2]=f2bf(v.z); d[3]=f2bf(v.w);
        }
        __syncthreads();

        const int lane = tid & 63, wave = tid >> 6;
        const int q = lane >> 4, m = lane & 15;

        // H-GEMM: [32 x 192] @ [192 x 256]
        bf16x8 a[2][6];
        #pragma unroll
        for (int rs = 0; rs < 2; ++rs)
            #pragma unroll
            for (int ks = 0; ks < 6; ++ks) {
                int row = rs*16 + m;
                int k = ks*32 + q*8;
                a[rs][ks] = *(const bf16x8*)&xwin[(row + (k >> 6))*72 + (k & 63)];
            }

        #pragma unroll
        for (int cs = 0; cs < 4; ++cs) {
            const int c0 = (wave*4 + cs)*16;
            bf16x8 bw[6];
            #pragma unroll
            for (int ks = 0; ks < 6; ++ks)
                bw[ks] = *(const bf16x8*)(WcatT + (size_t)(c0 + m)*192 + ks*32 + q*8);
            f32x4 acc0 = {0.f,0.f,0.f,0.f}, acc1 = {0.f,0.f,0.f,0.f};
            #pragma unroll
            for (int ks = 0; ks < 6; ++ks) {
                acc0 = __builtin_amdgcn_mfma_f32_16x16x32_bf16(a[0][ks], bw[ks], acc0, 0, 0, 0);
                acc1 = __builtin_amdgcn_mfma_f32_16x16x32_bf16(a[1][ks], bw[ks], acc1, 0, 0, 0);
            }
            const int c = c0 + m;
            const float bias = (c < 128) ? bl[c] : br[c - 128];
            #pragma unroll
            for (int r = 0; r < 4; ++r) {
                Hbuf[(q*4 + r)*264 + c]      = f2bf(fmaxf(acc0[r] + bias, 0.f));
                Hbuf[(16 + q*4 + r)*264 + c] = f2bf(fmaxf(acc1[r] + bias, 0.f));
            }
        }
        __syncthreads();

        // hr store: 32 rows x 128 bf16 = 512 chunks of 8
        for (int c = tid; c < 512; c += 256) {
            int row = c >> 4, ch = c & 15;
            bf16x8 v = *(const bf16x8*)&Hbuf[row*264 + 128 + ch*8];
            *(bf16x8*)(hr_ws + ((size_t)(b1*1024 + n0 + row))*128 + ch*8) = v;
        }

        // T-GEMM: [32 x 128(hl)] @ [128 x 256]
        bf16x8 a2[2][4];
        #pragma unroll
        for (int rs = 0; rs < 2; ++rs)
            #pragma unroll
            for (int ks = 0; ks < 4; ++ks)
                a2[rs][ks] = *(const bf16x8*)&Hbuf[(rs*16 + m)*264 + ks*32 + q*8];

        #pragma unroll
        for (int cs = 0; cs < 4; ++cs) {
            const int c0 = (wave*4 + cs)*16;
            bf16x8 bw[4];
            #pragma unroll
            for (int ks = 0; ks < 4; ++ks)
                bw[ks] = *(const bf16x8*)(WtT + (size_t)(c0 + m)*128 + ks*32 + q*8);
            f32x4 acc0 = {0.f,0.f,0.f,0.f}, acc1 = {0.f,0.f,0.f,0.f};
            #pragma unroll
            for (int ks = 0; ks < 4; ++ks) {
                acc0 = __builtin_amdgcn_mfma_f32_16x16x32_bf16(a2[0][ks], bw[ks], acc0, 0, 0, 0);
                acc1 = __builtin_amdgcn_mfma_f32_16x16x32_bf16(a2[1][ks], bw[ks], acc1, 0, 0, 0);
            }
            const int c = c0 + m;
            #pragma unroll
            for (int r = 0; r < 4; ++r) {
                Tbuf[(q*4 + r)*264 + c]      = f2bf(acc0[r]);
                Tbuf[(16 + q*4 + r)*264 + c] = f2bf(acc1[r]);
            }
        }
        __syncthreads();

        // T store: 32 rows x 256 bf16 = 1024 chunks of 8
        for (int c = tid; c < 1024; c += 256) {
            int row = c >> 5, ch = c & 31;
            bf16x8 v = *(const bf16x8*)&Tbuf[row*264 + ch*8];
            *(bf16x8*)(t_ws + ((size_t)(b1*1024 + n0 + row))*256 + ch*8) = v;
        }
    }
    __threadfence();
    grid.sync();

    // ======================= Phase 2: pairwise GEMM ========================
    // blk = b*32 + r; r: tj = r>>2 (8 j-tiles), ig = r&3; 4 reps cover the
    // 16 i-tiles: i0 = ig*256 + rep*64. All 4 reps share (b, j0) -> hr reuse.
    {
        const int lane = tid & 63, wave = tid >> 6;
        const int q = lane >> 4, m = lane & 15;
        const int b2 = blk >> 5;
        const int r_ = blk & 31;
        const int j0 = (r_ >> 2)*128 + (wave >> 1)*64;
        const int ig = r_ & 3;

        const unsigned short* tb = t_ws  + (size_t)b2*1024*256;
        const unsigned short* hb = hr_ws + (size_t)b2*1024*128;
        const float bb0 = bbil[0], bb1 = bbil[1];

        #pragma unroll
        for (int rep = 0; rep < 4; ++rep) {
            const int i0 = ig*256 + rep*64 + (wave & 1)*32;

            f32x4 acc[2][2][4];
            #pragma unroll
            for (int ch = 0; ch < 2; ++ch)
                #pragma unroll
                for (int is = 0; is < 2; ++is)
                    #pragma unroll
                    for (int js = 0; js < 4; ++js)
                        acc[ch][is][js] = (f32x4){0.f,0.f,0.f,0.f};

            #pragma unroll
            for (int ks = 0; ks < 4; ++ks) {
                bf16x8 af[2][2], bfr[4];
                #pragma unroll
                for (int is = 0; is < 2; ++is) {
                    const unsigned short* rp = tb + (size_t)(i0 + is*16 + m)*256 + ks*32 + q*8;
                    af[0][is] = *(const bf16x8*)(rp);
                    af[1][is] = *(const bf16x8*)(rp + 128);
                }
                #pragma unroll
                for (int js = 0; js < 4; ++js)
                    bfr[js] = *(const bf16x8*)(hb + (size_t)(j0 + js*16 + m)*128 + ks*32 + q*8);

                #pragma unroll
                for (int ch = 0; ch < 2; ++ch)
                    #pragma unroll
                    for (int is = 0; is < 2; ++is)
                        #pragma unroll
                        for (int js = 0; js < 4; ++js)
                            acc[ch][is][js] = __builtin_amdgcn_mfma_f32_16x16x32_bf16(
                                af[ch][is], bfr[js], acc[ch][is][js], 0, 0, 0);
            }

            #pragma unroll
            for (int is = 0; is < 2; ++is)
                #pragma unroll
                for (int js = 0; js < 4; ++js)
                    #pragma unroll
                    for (int rr = 0; rr < 4; ++rr) {
                        int i = i0 + is*16 + q*4 + rr;
                        int j = j0 + js*16 + m;
                        f32x2 v = { acc[0][is][js][rr] + bb0, acc[1][is][js][rr] + bb1 };
                        __builtin_nontemporal_store(
                            v, (f32x2*)(out + ((size_t)(b2*1024 + i)*1024 + j)*2));
                    }
        }
    }
}

// ===========================================================================
// Fallback path: the round-4 passing 3-kernel pipeline (unchanged).
// ===========================================================================
__global__ void prep_kernel(const float* __restrict__ Wl,
                            const float* __restrict__ Wr,
                            const float* __restrict__ Wb,
                            unsigned short* __restrict__ WcatT,
                            unsigned short* __restrict__ WtT)
{
    int i = blockIdx.x * 256 + threadIdx.x;
    const int TOT = 256*192 + 256*128;
    if (i >= TOT) return;
    if (i < 256*192) {
        int c = i / 192, kk = i % 192;
        float v;
        if (c < 128) {
            int orig = (kk < 64) ? (kk + 64) : ((kk < 128) ? (kk - 64) : kk);
            v = Wl[c*192 + orig];
        } else {
            int orig = (kk < 64) ? (kk + 128) : (kk - 64);
            v = Wr[(c-128)*192 + orig];
        }
        WcatT[i] = f2bf(v);
    } else {
        int j = i - 256*192;
        int c = j >> 7, h = j & 127;
        int k = c >> 7, g = c & 127;
        WtT[j] = f2bf(Wb[(k*128 + h)*128 + g]);
    }
}

__global__ __launch_bounds__(256) void stage1_kernel(
    const float* __restrict__ x,
    const float* __restrict__ bl,
    const float* __restrict__ br,
    const unsigned short* __restrict__ WcatT,
    const unsigned short* __restrict__ WtT,
    unsigned short* __restrict__ t_out,
    unsigned short* __restrict__ hr_out)
{
    __shared__ unsigned short xwin[18*72];
    __shared__ unsigned short Hbuf[16*264];
    __shared__ unsigned short Tbuf[16*264];

    const int tid = threadIdx.x;
    const int blk = blockIdx.x;
    const int b   = blk >> 6;
    const int n0  = (blk & 63) << 4;

    for (int c = tid; c < 18*16; c += 256) {
        int row = c >> 4, ch = c & 15;
        int n = n0 - 1 + row;
        float4 v = make_float4(0.f, 0.f, 0.f, 0.f);
        if (n >= 0 && n < 1024)
            v = ((const float4*)(x + ((size_t)b*1024 + n)*64))[ch];
        unsigned short* d = &xwin[row*72 + ch*4];
        d[0]=f2bf(v.x); d[1]=f2bf(v.y); d[2]=f2bf(v.z); d[3]=f2bf(v.w);
    }
    __syncthreads();

    const int lane = tid & 63, wave = tid >> 6;
    const int q = lane >> 4, m = lane & 15;

    bf16x8 a[6];
    #pragma unroll
    for (int ks = 0; ks < 6; ++ks) {
        int k = ks*32 + q*8;
        a[ks] = *(const bf16x8*)&xwin[(m + (k >> 6))*72 + (k & 63)];
    }

    #pragma unroll
    for (int cs = 0; cs < 4; ++cs) {
        const int c0 = (wave*4 + cs)*16;
        bf16x8 bw[6];
        #pragma unroll
        for (int ks = 0; ks < 6; ++ks)
            bw[ks] = *(const bf16x8*)(WcatT + (size_t)(c0 + m)*192 + ks*32 + q*8);
        f32x4 acc0 = {0.f,0.f,0.f,0.f};
        #pragma unroll
        for (int ks = 0; ks < 6; ++ks)
            acc0 = __builtin_amdgcn_mfma_f32_16x16x32_bf16(a[ks], bw[ks], acc0, 0, 0, 0);
        const int c = c0 + m;
        const float bias = (c < 128) ? bl[c] : br[c - 128];
        #pragma unroll
        for (int r = 0; r < 4; ++r)
            Hbuf[(q*4 + r)*264 + c] = f2bf(fmaxf(acc0[r] + bias, 0.f));
    }
    __syncthreads();

    {
        int row = tid >> 4, ch = tid & 15;
        bf16x8 v = *(const bf16x8*)&Hbuf[row*264 + 128 + ch*8];
        *(bf16x8*)(hr_out + ((size_t)(b*1024 + n0 + row))*128 + ch*8) = v;
    }

    bf16x8 a2[4];
    #pragma unroll
    for (int ks = 0; ks < 4; ++ks)
        a2[ks] = *(const bf16x8*)&Hbuf[m*264 + ks*32 + q*8];

    #pragma unroll
    for (int cs = 0; cs < 4; ++cs) {
        const int c0 = (wave*4 + cs)*16;
        bf16x8 bw[4];
        #pragma unroll
        for (int ks = 0; ks < 4; ++ks)
            bw[ks] = *(const bf16x8*)(WtT + (size_t)(c0 + m)*128 + ks*32 + q*8);
        f32x4 acc0 = {0.f,0.f,0.f,0.f};
        #pragma unroll
        for (int ks = 0; ks < 4; ++ks)
            acc0 = __builtin_amdgcn_mfma_f32_16x16x32_bf16(a2[ks], bw[ks], acc0, 0, 0, 0);
        const int c = c0 + m;
        #pragma unroll
        for (int r = 0; r < 4; ++r)
            Tbuf[(q*4 + r)*264 + c] = f2bf(acc0[r]);
    }
    __syncthreads();

    for (int c = tid; c < 512; c += 256) {
        int row = c >> 5, ch = c & 31;
        bf16x8 v = *(const bf16x8*)&Tbuf[row*264 + ch*8];
        *(bf16x8*)(t_out + ((size_t)(b*1024 + n0 + row))*256 + ch*8) = v;
    }
}

__global__ __launch_bounds__(256) void stage2_kernel(
    const unsigned short* __restrict__ t_in,
    const unsigned short* __restrict__ hr_in,
    const float* __restrict__ bbil,
    float* __restrict__ out)
{
    const int b = blockIdx.z;
    const int tid = threadIdx.x, lane = tid & 63, wave = tid >> 6;
    const int q = lane >> 4, m = lane & 15;
    const int i0 = blockIdx.x*64 + (wave & 1)*32;
    const int j0 = blockIdx.y*128 + (wave >> 1)*64;

    const unsigned short* tb = t_in  + (size_t)b*1024*256;
    const unsigned short* hb = hr_in + (size_t)b*1024*128;

    f32x4 acc[2][2][4];
    #pragma unroll
    for (int ch = 0; ch < 2; ++ch)
        #pragma unroll
        for (int is = 0; is < 2; ++is)
            #pragma unroll
            for (int js = 0; js < 4; ++js)
                acc[ch][is][js] = (f32x4){0.f,0.f,0.f,0.f};

    #pragma unroll
    for (int ks = 0; ks < 4; ++ks) {
        bf16x8 af[2][2], bfr[4];
        #pragma unroll
        for (int is = 0; is < 2; ++is) {
            const unsigned short* rp = tb + (size_t)(i0 + is*16 + m)*256 + ks*32 + q*8;
            af[0][is] = *(const bf16x8*)(rp);
            af[1][is] = *(const bf16x8*)(rp + 128);
        }
        #pragma unroll
        for (int js = 0; js < 4; ++js)
            bfr[js] = *(const bf16x8*)(hb + (size_t)(j0 + js*16 + m)*128 + ks*32 + q*8);

        #pragma unroll
        for (int ch = 0; ch < 2; ++ch)
            #pragma unroll
            for (int is = 0; is < 2; ++is)
                #pragma unroll
                for (int js = 0; js < 4; ++js)
                    acc[ch][is][js] = __builtin_amdgcn_mfma_f32_16x16x32_bf16(
                        af[ch][is], bfr[js], acc[ch][is][js], 0, 0, 0);
    }

    const float bb0 = bbil[0], bb1 = bbil[1];
    #pragma unroll
    for (int is = 0; is < 2; ++is)
        #pragma unroll
        for (int js = 0; js < 4; ++js)
            #pragma unroll
            for (int r = 0; r < 4; ++r) {
                int i = i0 + is*16 + q*4 + r;
                int j = j0 + js*16 + m;
                f32x2 v = { acc[0][is][js][r] + bb0, acc[1][is][js][r] + bb1 };
                __builtin_nontemporal_store(
                    v, (f32x2*)(out + ((size_t)(b*1024 + i)*1024 + j)*2));
            }
}

extern "C" void kernel_launch(void* const* d_in, const int* in_sizes, int n_in,
                              void* d_out, int out_size, void* d_ws, size_t ws_size,
                              hipStream_t stream)
{
    const float* x    = (const float*)d_in[0];
    const float* Wl   = (const float*)d_in[1];
    const float* bl   = (const float*)d_in[2];
    const float* Wr   = (const float*)d_in[3];
    const float* br   = (const float*)d_in[4];
    const float* Wb   = (const float*)d_in[5];
    const float* bbil = (const float*)d_in[6];
    float* out = (float*)d_out;

    unsigned char* ws = (unsigned char*)d_ws;
    unsigned short* t_ws  = (unsigned short*)(ws);                      // 4 MiB
    unsigned short* hr_ws = (unsigned short*)(ws + (4u<<20));           // 2 MiB
    unsigned short* WcatT = (unsigned short*)(ws + (6u<<20));           // 96 KiB
    unsigned short* WtT   = (unsigned short*)(ws + (6u<<20) + 98304);   // 64 KiB

    void* args[] = { (void*)&x, (void*)&Wl, (void*)&bl, (void*)&Wr, (void*)&br,
                     (void*)&Wb, (void*)&bbil, (void*)&out,
                     (void*)&WcatT, (void*)&WtT, (void*)&t_ws, (void*)&hr_ws };
    hipError_t err = hipLaunchCooperativeKernel((const void*)fused_kernel,
                                                dim3(256), dim3(256), args, 0, stream);
    if (err != hipSuccess) {
        (void)hipGetLastError();   // clear sticky error, use fallback pipeline
        prep_kernel<<<320, 256, 0, stream>>>(Wl, Wr, Wb, WcatT, WtT);
        stage1_kernel<<<512, 256, 0, stream>>>(x, bl, br, WcatT, WtT, t_ws, hr_ws);
        stage2_kernel<<<dim3(16, 8, 8), 256, 0, stream>>>(t_ws, hr_ws, bbil, out);
    }
}

// Round 7
// 121.545 us; speedup vs baseline: 1.7839x; 1.7839x over previous
//
#include <hip/hip_runtime.h>
#include <hip/hip_bf16.h>

typedef __attribute__((ext_vector_type(8))) __bf16 bf16x8;
typedef __attribute__((ext_vector_type(4))) float f32x4;
typedef __attribute__((ext_vector_type(2))) float f32x2;

#define DEVI static __device__ __forceinline__

DEVI unsigned short f2bf(float f) {
    union { float f; unsigned int u; } v; v.f = f;
    unsigned int u = v.u;
    u += 0x7FFFu + ((u >> 16) & 1u);   // RNE
    return (unsigned short)(u >> 16);
}

// ===========================================================================
// Index maps (verified passing rounds 3/4/6):
//  WcatT[256][192]: col c<128 -> W_l row c, c>=128 -> W_r row c-128.
//  Packed K order = window order [x(n-1) | x(n) | x(n+1)].
//   W_l map: 0:64<-feat 64:128, 64:128<-feat 0:64, 128:192<-feat 128:192
//   W_r map: 0:64<-feat 128:192, 64:192<-feat 0:128
//  WtT[256][128]: c = k*128+g, WtT[c][h] = W_bil[k][h][g]
//  MFMA 16x16x32 bf16: A[m=lane&15][k=q*8+j], B[k=q*8+j][n=lane&15],
//                      D[row=q*4+r][col=lane&15]
// ===========================================================================

__global__ void prep_kernel(const float* __restrict__ Wl,
                            const float* __restrict__ Wr,
                            const float* __restrict__ Wb,
                            unsigned short* __restrict__ WcatT,
                            unsigned short* __restrict__ WtT)
{
    int i = blockIdx.x * 256 + threadIdx.x;
    const int TOT = 256*192 + 256*128;
    if (i >= TOT) return;
    if (i < 256*192) {
        int c = i / 192, kk = i % 192;
        float v;
        if (c < 128) {
            int orig = (kk < 64) ? (kk + 64) : ((kk < 128) ? (kk - 64) : kk);
            v = Wl[c*192 + orig];
        } else {
            int orig = (kk < 64) ? (kk + 128) : (kk - 64);
            v = Wr[(c-128)*192 + orig];
        }
        WcatT[i] = f2bf(v);
    } else {
        int j = i - 256*192;
        int c = j >> 7, h = j & 127;
        int k = c >> 7, g = c & 127;
        WtT[j] = f2bf(Wb[(k*128 + h)*128 + g]);
    }
}

// ---------------------------------------------------------------------------
// stage 1: 16 rows/block, 512 blocks (2 blocks/CU).
// ---------------------------------------------------------------------------
__global__ __launch_bounds__(256) void stage1_kernel(
    const float* __restrict__ x,
    const float* __restrict__ bl,
    const float* __restrict__ br,
    const unsigned short* __restrict__ WcatT,
    const unsigned short* __restrict__ WtT,
    unsigned short* __restrict__ t_out,   // [B*N][256], c = k*128+g
    unsigned short* __restrict__ hr_out)  // [B*N][128]
{
    __shared__ unsigned short xwin[18*72];
    __shared__ unsigned short Hbuf[16*264];
    __shared__ unsigned short Tbuf[16*264];

    const int tid = threadIdx.x;
    const int blk = blockIdx.x;
    const int b   = blk >> 6;
    const int n0  = (blk & 63) << 4;

    for (int c = tid; c < 18*16; c += 256) {
        int row = c >> 4, ch = c & 15;
        int n = n0 - 1 + row;
        float4 v = make_float4(0.f, 0.f, 0.f, 0.f);
        if (n >= 0 && n < 1024)
            v = ((const float4*)(x + ((size_t)b*1024 + n)*64))[ch];
        unsigned short* d = &xwin[row*72 + ch*4];
        d[0]=f2bf(v.x); d[1]=f2bf(v.y); d[2]=f2bf(v.z); d[3]=f2bf(v.w);
    }
    __syncthreads();

    const int lane = tid & 63, wave = tid >> 6;
    const int q = lane >> 4, m = lane & 15;

    // H-GEMM: [16 x 192] @ [192 x 256]
    bf16x8 a[6];
    #pragma unroll
    for (int ks = 0; ks < 6; ++ks) {
        int k = ks*32 + q*8;
        a[ks] = *(const bf16x8*)&xwin[(m + (k >> 6))*72 + (k & 63)];
    }

    #pragma unroll
    for (int cs = 0; cs < 4; ++cs) {
        const int c0 = (wave*4 + cs)*16;
        bf16x8 bw[6];
        #pragma unroll
        for (int ks = 0; ks < 6; ++ks)
            bw[ks] = *(const bf16x8*)(WcatT + (size_t)(c0 + m)*192 + ks*32 + q*8);
        f32x4 acc0 = {0.f,0.f,0.f,0.f};
        #pragma unroll
        for (int ks = 0; ks < 6; ++ks)
            acc0 = __builtin_amdgcn_mfma_f32_16x16x32_bf16(a[ks], bw[ks], acc0, 0, 0, 0);
        const int c = c0 + m;
        const float bias = (c < 128) ? bl[c] : br[c - 128];
        #pragma unroll
        for (int r = 0; r < 4; ++r)
            Hbuf[(q*4 + r)*264 + c] = f2bf(fmaxf(acc0[r] + bias, 0.f));
    }
    __syncthreads();

    // hr store: 16 rows x 128 bf16 = 256 chunks of 8 (tid-exact)
    {
        int row = tid >> 4, ch = tid & 15;
        bf16x8 v = *(const bf16x8*)&Hbuf[row*264 + 128 + ch*8];
        *(bf16x8*)(hr_out + ((size_t)(b*1024 + n0 + row))*128 + ch*8) = v;
    }

    // T-GEMM: [16 x 128(hl)] @ [128 x 256]
    bf16x8 a2[4];
    #pragma unroll
    for (int ks = 0; ks < 4; ++ks)
        a2[ks] = *(const bf16x8*)&Hbuf[m*264 + ks*32 + q*8];

    #pragma unroll
    for (int cs = 0; cs < 4; ++cs) {
        const int c0 = (wave*4 + cs)*16;
        bf16x8 bw[4];
        #pragma unroll
        for (int ks = 0; ks < 4; ++ks)
            bw[ks] = *(const bf16x8*)(WtT + (size_t)(c0 + m)*128 + ks*32 + q*8);
        f32x4 acc0 = {0.f,0.f,0.f,0.f};
        #pragma unroll
        for (int ks = 0; ks < 4; ++ks)
            acc0 = __builtin_amdgcn_mfma_f32_16x16x32_bf16(a2[ks], bw[ks], acc0, 0, 0, 0);
        const int c = c0 + m;
        #pragma unroll
        for (int r = 0; r < 4; ++r)
            Tbuf[(q*4 + r)*264 + c] = f2bf(acc0[r]);
    }
    __syncthreads();

    for (int c = tid; c < 512; c += 256) {
        int row = c >> 5, ch = c & 31;
        bf16x8 v = *(const bf16x8*)&Tbuf[row*264 + ch*8];
        *(bf16x8*)(t_out + ((size_t)(b*1024 + n0 + row))*256 + ch*8) = v;
    }
}

// ---------------------------------------------------------------------------
// stage 2: out[b,i,j,k] = sum_g t[b,i,k,g]*hr[b,j,g] + b_bil[k]
// Round-7 retile for occupancy + L2 locality:
//  grid (8 b, 16 i, 16 j) = 2048 blocks — b on x so consecutive blocks land
//  on different XCDs (blk%8): each XCD works one batch (768 KiB << 4 MiB L2).
//  block 256 thr = 4 waves in 2x2 -> block tile 64i x 64j.
//  wave tile 32i x 32j x 2k: acc 2ch x 2is x 2js x f32x4 = 32 VGPR (was 64);
//  __launch_bounds__(256,4) -> <=128 VGPR -> 4 waves/SIMD (was ~2).
// ---------------------------------------------------------------------------
__global__ __launch_bounds__(256, 4) void stage2_kernel(
    const unsigned short* __restrict__ t_in,   // [B*N][256]
    const unsigned short* __restrict__ hr_in,  // [B*N][128]
    const float* __restrict__ bbil,            // [2]
    float* __restrict__ out)                   // [B][N][N][2]
{
    const int b = blockIdx.x;
    const int tid = threadIdx.x, lane = tid & 63, wave = tid >> 6;
    const int q = lane >> 4, m = lane & 15;
    const int i0 = blockIdx.y*64 + (wave & 1)*32;
    const int j0 = blockIdx.z*64 + (wave >> 1)*32;

    const unsigned short* tb = t_in  + (size_t)b*1024*256;
    const unsigned short* hb = hr_in + (size_t)b*1024*128;

    f32x4 acc[2][2][2];   // [ch][is][js]
    #pragma unroll
    for (int ch = 0; ch < 2; ++ch)
        #pragma unroll
        for (int is = 0; is < 2; ++is)
            #pragma unroll
            for (int js = 0; js < 2; ++js)
                acc[ch][is][js] = (f32x4){0.f,0.f,0.f,0.f};

    #pragma unroll
    for (int ks = 0; ks < 4; ++ks) {
        bf16x8 af[2][2], bfr[2];
        #pragma unroll
        for (int is = 0; is < 2; ++is) {
            const unsigned short* rp = tb + (size_t)(i0 + is*16 + m)*256 + ks*32 + q*8;
            af[0][is] = *(const bf16x8*)(rp);
            af[1][is] = *(const bf16x8*)(rp + 128);
        }
        #pragma unroll
        for (int js = 0; js < 2; ++js)
            bfr[js] = *(const bf16x8*)(hb + (size_t)(j0 + js*16 + m)*128 + ks*32 + q*8);

        #pragma unroll
        for (int ch = 0; ch < 2; ++ch)
            #pragma unroll
            for (int is = 0; is < 2; ++is)
                #pragma unroll
                for (int js = 0; js < 2; ++js)
                    acc[ch][is][js] = __builtin_amdgcn_mfma_f32_16x16x32_bf16(
                        af[ch][is], bfr[js], acc[ch][is][js], 0, 0, 0);
    }

    const float bb0 = bbil[0], bb1 = bbil[1];
    #pragma unroll
    for (int is = 0; is < 2; ++is)
        #pragma unroll
        for (int js = 0; js < 2; ++js)
            #pragma unroll
            for (int r = 0; r < 4; ++r) {
                int i = i0 + is*16 + q*4 + r;
                int j = j0 + js*16 + m;
                f32x2 v = { acc[0][is][js][r] + bb0, acc[1][is][js][r] + bb1 };
                __builtin_nontemporal_store(
                    v, (f32x2*)(out + ((size_t)(b*1024 + i)*1024 + j)*2));
            }
}

extern "C" void kernel_launch(void* const* d_in, const int* in_sizes, int n_in,
                              void* d_out, int out_size, void* d_ws, size_t ws_size,
                              hipStream_t stream)
{
    const float* x    = (const float*)d_in[0];
    const float* Wl   = (const float*)d_in[1];
    const float* bl   = (const float*)d_in[2];
    const float* Wr   = (const float*)d_in[3];
    const float* br   = (const float*)d_in[4];
    const float* Wb   = (const float*)d_in[5];
    const float* bbil = (const float*)d_in[6];
    float* out = (float*)d_out;

    unsigned char* ws = (unsigned char*)d_ws;
    unsigned short* t_ws  = (unsigned short*)(ws);                      // 4 MiB
    unsigned short* hr_ws = (unsigned short*)(ws + (4u<<20));           // 2 MiB
    unsigned short* WcatT = (unsigned short*)(ws + (6u<<20));           // 96 KiB
    unsigned short* WtT   = (unsigned short*)(ws + (6u<<20) + 98304);   // 64 KiB

    prep_kernel<<<320, 256, 0, stream>>>(Wl, Wr, Wb, WcatT, WtT);
    stage1_kernel<<<512, 256, 0, stream>>>(x, bl, br, WcatT, WtT, t_ws, hr_ws);
    stage2_kernel<<<dim3(8, 16, 16), 256, 0, stream>>>(t_ws, hr_ws, bbil, out);
}

// Round 8
// 114.477 us; speedup vs baseline: 1.8941x; 1.0617x over previous
//
#include <hip/hip_runtime.h>
#include <hip/hip_bf16.h>

typedef __attribute__((ext_vector_type(8))) __bf16 bf16x8;
typedef __attribute__((ext_vector_type(4))) float f32x4;

#define DEVI static __device__ __forceinline__

DEVI unsigned short f2bf(float f) {
    union { float f; unsigned int u; } v; v.f = f;
    unsigned int u = v.u;
    u += 0x7FFFu + ((u >> 16) & 1u);   // RNE
    return (unsigned short)(u >> 16);
}

// ===========================================================================
// Round-8 = exact revert to the round-3 configuration (best measured:
// 114.9 µs total ≈ 96.4 µs harness-fixed + 18.5 µs kernels, ~1.5 µs above
// the modeled kernel floor). R4/R7 occupancy/NT-store changes all regressed.
//
// Index maps (verified passing rounds 3/4/6/7):
//  WcatT[256][192]: col c<128 -> W_l row c, c>=128 -> W_r row c-128.
//  Packed K order = window order [x(n-1) | x(n) | x(n+1)].
//   W_l map: 0:64<-feat 64:128, 64:128<-feat 0:64, 128:192<-feat 128:192
//   W_r map: 0:64<-feat 128:192, 64:192<-feat 0:128
//  WtT[256][128]: c = k*128+g, WtT[c][h] = W_bil[k][h][g]
//  MFMA 16x16x32 bf16: A[m=lane&15][k=q*8+j], B[k=q*8+j][n=lane&15],
//                      D[row=q*4+r][col=lane&15]
// ===========================================================================

__global__ void prep_kernel(const float* __restrict__ Wl,
                            const float* __restrict__ Wr,
                            const float* __restrict__ Wb,
                            unsigned short* __restrict__ WcatT,
                            unsigned short* __restrict__ WtT)
{
    int i = blockIdx.x * 256 + threadIdx.x;
    const int TOT = 256*192 + 256*128;
    if (i >= TOT) return;
    if (i < 256*192) {
        int c = i / 192, kk = i % 192;
        float v;
        if (c < 128) {
            int orig = (kk < 64) ? (kk + 64) : ((kk < 128) ? (kk - 64) : kk);
            v = Wl[c*192 + orig];
        } else {
            int orig = (kk < 64) ? (kk + 128) : (kk - 64);
            v = Wr[(c-128)*192 + orig];
        }
        WcatT[i] = f2bf(v);
    } else {
        int j = i - 256*192;
        int c = j >> 7, h = j & 127;
        int k = c >> 7, g = c & 127;
        WtT[j] = f2bf(Wb[(k*128 + h)*128 + g]);
    }
}

// ---------------------------------------------------------------------------
// stage 1: 32 rows per block, 256 blocks (R3 geometry — measured best).
// ---------------------------------------------------------------------------
__global__ __launch_bounds__(256) void stage1_kernel(
    const float* __restrict__ x,
    const float* __restrict__ bl,
    const float* __restrict__ br,
    const unsigned short* __restrict__ WcatT,
    const unsigned short* __restrict__ WtT,
    unsigned short* __restrict__ t_out,   // [B*N][256], c = k*128+g
    unsigned short* __restrict__ hr_out)  // [B*N][128]
{
    __shared__ unsigned short xwin[34*72];   // rows padded 64->72
    __shared__ unsigned short Hbuf[32*264];  // 256 -> 264 pad
    __shared__ unsigned short Tbuf[32*264];

    const int tid = threadIdx.x;
    const int blk = blockIdx.x;           // 256 blocks, 32 per batch
    const int b   = blk >> 5;
    const int n0  = (blk & 31) << 5;

    // ---- 1) load x window rows n0-1 .. n0+32 (zero outside batch) ----
    for (int c = tid; c < 34*16; c += 256) {
        int row = c >> 4, ch = c & 15;
        int n = n0 - 1 + row;
        float4 v = make_float4(0.f, 0.f, 0.f, 0.f);
        if (n >= 0 && n < 1024)
            v = ((const float4*)(x + ((size_t)b*1024 + n)*64))[ch];
        unsigned short* d = &xwin[row*72 + ch*4];
        d[0]=f2bf(v.x); d[1]=f2bf(v.y); d[2]=f2bf(v.z); d[3]=f2bf(v.w);
    }
    __syncthreads();

    const int lane = tid & 63, wave = tid >> 6;
    const int q = lane >> 4, m = lane & 15;

    // ---- 2) H-GEMM: [32 x 192] @ [192 x 256] ----
    bf16x8 a[2][6];
    #pragma unroll
    for (int rs = 0; rs < 2; ++rs)
        #pragma unroll
        for (int ks = 0; ks < 6; ++ks) {
            int row = rs*16 + m;
            int k = ks*32 + q*8;
            a[rs][ks] = *(const bf16x8*)&xwin[(row + (k >> 6))*72 + (k & 63)];
        }

    #pragma unroll
    for (int cs = 0; cs < 4; ++cs) {
        const int c0 = (wave*4 + cs)*16;
        bf16x8 bw[6];
        #pragma unroll
        for (int ks = 0; ks < 6; ++ks)
            bw[ks] = *(const bf16x8*)(WcatT + (size_t)(c0 + m)*192 + ks*32 + q*8);
        f32x4 acc0 = {0.f,0.f,0.f,0.f}, acc1 = {0.f,0.f,0.f,0.f};
        #pragma unroll
        for (int ks = 0; ks < 6; ++ks) {
            acc0 = __builtin_amdgcn_mfma_f32_16x16x32_bf16(a[0][ks], bw[ks], acc0, 0, 0, 0);
            acc1 = __builtin_amdgcn_mfma_f32_16x16x32_bf16(a[1][ks], bw[ks], acc1, 0, 0, 0);
        }
        const int c = c0 + m;                    // D col = lane&15
        const float bias = (c < 128) ? bl[c] : br[c - 128];
        #pragma unroll
        for (int r = 0; r < 4; ++r) {
            Hbuf[(q*4 + r)*264 + c]      = f2bf(fmaxf(acc0[r] + bias, 0.f));
            Hbuf[(16 + q*4 + r)*264 + c] = f2bf(fmaxf(acc1[r] + bias, 0.f));
        }
    }
    __syncthreads();

    // ---- 3) hr store: 32 rows x 128 bf16 = 512 chunks of 8 ----
    for (int c = tid; c < 512; c += 256) {
        int row = c >> 4, ch = c & 15;
        bf16x8 v = *(const bf16x8*)&Hbuf[row*264 + 128 + ch*8];
        *(bf16x8*)(hr_out + ((size_t)(b*1024 + n0 + row))*128 + ch*8) = v;
    }

    // ---- 4) T-GEMM: [32 x 128(hl)] @ [128 x 256] ----
    bf16x8 a2[2][4];
    #pragma unroll
    for (int rs = 0; rs < 2; ++rs)
        #pragma unroll
        for (int ks = 0; ks < 4; ++ks)
            a2[rs][ks] = *(const bf16x8*)&Hbuf[(rs*16 + m)*264 + ks*32 + q*8];

    #pragma unroll
    for (int cs = 0; cs < 4; ++cs) {
        const int c0 = (wave*4 + cs)*16;
        bf16x8 bw[4];
        #pragma unroll
        for (int ks = 0; ks < 4; ++ks)
            bw[ks] = *(const bf16x8*)(WtT + (size_t)(c0 + m)*128 + ks*32 + q*8);
        f32x4 acc0 = {0.f,0.f,0.f,0.f}, acc1 = {0.f,0.f,0.f,0.f};
        #pragma unroll
        for (int ks = 0; ks < 4; ++ks) {
            acc0 = __builtin_amdgcn_mfma_f32_16x16x32_bf16(a2[0][ks], bw[ks], acc0, 0, 0, 0);
            acc1 = __builtin_amdgcn_mfma_f32_16x16x32_bf16(a2[1][ks], bw[ks], acc1, 0, 0, 0);
        }
        const int c = c0 + m;
        #pragma unroll
        for (int r = 0; r < 4; ++r) {
            Tbuf[(q*4 + r)*264 + c]      = f2bf(acc0[r]);
            Tbuf[(16 + q*4 + r)*264 + c] = f2bf(acc1[r]);
        }
    }
    __syncthreads();

    // ---- T store: 32 rows x 256 bf16 = 1024 chunks of 8 ----
    for (int c = tid; c < 1024; c += 256) {
        int row = c >> 5, ch = c & 31;
        bf16x8 v = *(const bf16x8*)&Tbuf[row*264 + ch*8];
        *(bf16x8*)(t_out + ((size_t)(b*1024 + n0 + row))*256 + ch*8) = v;
    }
}

// ---------------------------------------------------------------------------
// stage 2: out[b,i,j,k] = sum_g t[b,i,k,g]*hr[b,j,g] + b_bil[k]
// R3 geometry: grid (8 j, 16 i, 8 b), block 256 = 4 waves.
// block tile 64i x 128j; wave tile 32i x 64j x 2k. Direct L2 loads, no LDS.
// Plain f32x2 stores (NT stores measured slower in R4).
// ---------------------------------------------------------------------------
__global__ __launch_bounds__(256) void stage2_kernel(
    const unsigned short* __restrict__ t_in,   // [B*N][256]
    const unsigned short* __restrict__ hr_in,  // [B*N][128]
    const float* __restrict__ bbil,            // [2]
    float* __restrict__ out)                   // [B][N][N][2]
{
    const int b = blockIdx.z;
    const int tid = threadIdx.x, lane = tid & 63, wave = tid >> 6;
    const int q = lane >> 4, m = lane & 15;
    const int i0 = blockIdx.y*64 + (wave & 1)*32;
    const int j0 = blockIdx.x*128 + (wave >> 1)*64;

    const unsigned short* tb = t_in  + (size_t)b*1024*256;
    const unsigned short* hb = hr_in + (size_t)b*1024*128;

    f32x4 acc[2][2][4];
    #pragma unroll
    for (int ch = 0; ch < 2; ++ch)
        #pragma unroll
        for (int is = 0; is < 2; ++is)
            #pragma unroll
            for (int js = 0; js < 4; ++js)
                acc[ch][is][js] = (f32x4){0.f,0.f,0.f,0.f};

    #pragma unroll
    for (int ks = 0; ks < 4; ++ks) {
        bf16x8 af[2][2], bf[4];
        #pragma unroll
        for (int is = 0; is < 2; ++is) {
            const unsigned short* rp = tb + (size_t)(i0 + is*16 + m)*256 + ks*32 + q*8;
            af[0][is] = *(const bf16x8*)(rp);
            af[1][is] = *(const bf16x8*)(rp + 128);
        }
        #pragma unroll
        for (int js = 0; js < 4; ++js)
            bf[js] = *(const bf16x8*)(hb + (size_t)(j0 + js*16 + m)*128 + ks*32 + q*8);

        #pragma unroll
        for (int ch = 0; ch < 2; ++ch)
            #pragma unroll
            for (int is = 0; is < 2; ++is)
                #pragma unroll
                for (int js = 0; js < 4; ++js)
                    acc[ch][is][js] = __builtin_amdgcn_mfma_f32_16x16x32_bf16(
                        af[ch][is], bf[js], acc[ch][is][js], 0, 0, 0);
    }

    const float bb0 = bbil[0], bb1 = bbil[1];
    #pragma unroll
    for (int is = 0; is < 2; ++is)
        #pragma unroll
        for (int js = 0; js < 4; ++js)
            #pragma unroll
            for (int r = 0; r < 4; ++r) {
                int i = i0 + is*16 + q*4 + r;
                int j = j0 + js*16 + m;
                float2 v = make_float2(acc[0][is][js][r] + bb0,
                                       acc[1][is][js][r] + bb1);
                *(float2*)(out + ((size_t)(b*1024 + i)*1024 + j)*2) = v;
            }
}

extern "C" void kernel_launch(void* const* d_in, const int* in_sizes, int n_in,
                              void* d_out, int out_size, void* d_ws, size_t ws_size,
                              hipStream_t stream)
{
    const float* x    = (const float*)d_in[0];
    const float* Wl   = (const float*)d_in[1];
    const float* bl   = (const float*)d_in[2];
    const float* Wr   = (const float*)d_in[3];
    const float* br   = (const float*)d_in[4];
    const float* Wb   = (const float*)d_in[5];
    const float* bbil = (const float*)d_in[6];
    float* out = (float*)d_out;

    unsigned char* ws = (unsigned char*)d_ws;
    unsigned short* t_ws  = (unsigned short*)(ws);                      // 4 MiB
    unsigned short* hr_ws = (unsigned short*)(ws + (4u<<20));           // 2 MiB
    unsigned short* WcatT = (unsigned short*)(ws + (6u<<20));           // 96 KiB
    unsigned short* WtT   = (unsigned short*)(ws + (6u<<20) + 98304);   // 64 KiB

    prep_kernel<<<320, 256, 0, stream>>>(Wl, Wr, Wb, WcatT, WtT);
    stage1_kernel<<<256, 256, 0, stream>>>(x, bl, br, WcatT, WtT, t_ws, hr_ws);
    stage2_kernel<<<dim3(8, 16, 8), 256, 0, stream>>>(t_ws, hr_ws, bbil, out);
}